// Round 7
// baseline (2033.300 us; speedup 1.0000x reference)
//
#include <hip/hip_runtime.h>

#define NTOK 4096
#define EPS 1e-5f

// ---------------- K0: zero the stats accumulators ----------------
__global__ void k_zero(float* __restrict__ stats) {
    int t = blockIdx.x * blockDim.x + threadIdx.x;
    if (t < 1024) stats[t] = 0.0f;
}

// ---------------- K1: q = x @ Wq^T  (M=4096,N=512,K=512, all row-major K-contiguous)
__global__ __launch_bounds__(256) void k_gemm(const float* __restrict__ A,
                                              const float* __restrict__ B,
                                              float* __restrict__ C) {
    __shared__ float As[32][68];   // transposed: As[k][row]
    __shared__ float Bs[32][68];
    const int tid  = threadIdx.x;
    const int row0 = blockIdx.x * 64;
    const int col0 = blockIdx.y * 64;
    const int lr = tid >> 3;          // 0..31
    const int lc = (tid & 7) << 2;    // 0,4,...,28
    const int tx = tid & 15;
    const int ty = tid >> 4;
    float acc[4][4] = {};
    for (int kc = 0; kc < 512; kc += 32) {
        float4 a0 = *(const float4*)(A + (row0 + lr)      * 512 + kc + lc);
        float4 a1 = *(const float4*)(A + (row0 + lr + 32) * 512 + kc + lc);
        float4 b0 = *(const float4*)(B + (col0 + lr)      * 512 + kc + lc);
        float4 b1 = *(const float4*)(B + (col0 + lr + 32) * 512 + kc + lc);
        __syncthreads();
        As[lc + 0][lr] = a0.x; As[lc + 1][lr] = a0.y; As[lc + 2][lr] = a0.z; As[lc + 3][lr] = a0.w;
        As[lc + 0][lr + 32] = a1.x; As[lc + 1][lr + 32] = a1.y; As[lc + 2][lr + 32] = a1.z; As[lc + 3][lr + 32] = a1.w;
        Bs[lc + 0][lr] = b0.x; Bs[lc + 1][lr] = b0.y; Bs[lc + 2][lr] = b0.z; Bs[lc + 3][lr] = b0.w;
        Bs[lc + 0][lr + 32] = b1.x; Bs[lc + 1][lr + 32] = b1.y; Bs[lc + 2][lr + 32] = b1.z; Bs[lc + 3][lr + 32] = b1.w;
        __syncthreads();
        #pragma unroll
        for (int k = 0; k < 32; ++k) {
            const float4 av = *(const float4*)&As[k][ty << 2];
            const float4 bv = *(const float4*)&Bs[k][tx << 2];
            const float a[4] = {av.x, av.y, av.z, av.w};
            const float b[4] = {bv.x, bv.y, bv.z, bv.w};
            #pragma unroll
            for (int i = 0; i < 4; ++i)
                #pragma unroll
                for (int j = 0; j < 4; ++j)
                    acc[i][j] += a[i] * b[j];
        }
    }
    #pragma unroll
    for (int i = 0; i < 4; ++i) {
        float4 v = make_float4(acc[i][0], acc[i][1], acc[i][2], acc[i][3]);
        *(float4*)(C + (row0 + ty * 4 + i) * 512 + col0 + (tx << 2)) = v;
    }
}

// ---------------- K2: per-feature sum / sumsq over 4096 rows (atomics) ----------------
__global__ __launch_bounds__(256) void k_stats(const float* __restrict__ q,
                                               float* __restrict__ stats) {
    const int t  = threadIdx.x;
    const int r0 = blockIdx.x * 64;
    float s0 = 0.f, q0 = 0.f, s1 = 0.f, q1 = 0.f;
    for (int r = 0; r < 64; ++r) {
        const float a = q[(r0 + r) * 512 + t];
        const float b = q[(r0 + r) * 512 + 256 + t];
        s0 += a; q0 += a * a;
        s1 += b; q1 += b * b;
    }
    atomicAdd(&stats[t], s0);
    atomicAdd(&stats[t + 256], s1);
    atomicAdd(&stats[512 + t], q0);
    atomicAdd(&stats[512 + t + 256], q1);
}

// ---------------- K2b: finalize mean / rstd ----------------
__global__ void k_finalize(const float* __restrict__ stats, float* __restrict__ mr) {
    const int f = threadIdx.x;   // 512 threads
    const float mean = stats[f] * (1.0f / 4096.0f);
    const float var  = stats[512 + f] * (1.0f / 4096.0f) - mean * mean;
    mr[f]       = mean;
    mr[512 + f] = rsqrtf(var + EPS);
}

// ---------------- K3: fused per-token PKM, 4 waves, ILP-interleaved top-k chains ----------------
__global__ __launch_bounds__(256, 4) void k_pkm(
    const float* __restrict__ q,
    const float* __restrict__ mr,
    const float* __restrict__ gamma,
    const float* __restrict__ beta,
    const float* __restrict__ keys,
    const float* __restrict__ values,
    float* __restrict__ out)
{
    __shared__ float qn[512];
    __shared__ float sTopS[16][16];
    __shared__ int   sTopI[16][16];
    __shared__ float wW[128];
    __shared__ int   wI[128];

    const int tok  = blockIdx.x;
    const int tid  = threadIdx.x;
    const int lane = tid & 63;
    const int wave = tid >> 6;       // 0..3

    // normalize this token's q row
    {
        const float v0 = q[tok * 512 + tid];
        const float v1 = q[tok * 512 + 256 + tid];
        qn[tid]       = (v0 - mr[tid]) * mr[512 + tid] * gamma[tid] + beta[tid];
        qn[tid + 256] = (v1 - mr[tid + 256]) * mr[512 + tid + 256] * gamma[tid + 256] + beta[tid + 256];
    }
    __syncthreads();

    // ---- phase 1 dots: 4 slices per wave -> cand[4][4] ----
    unsigned long long cand[4][4];
    #pragma unroll
    for (int s4 = 0; s4 < 4; ++s4) {
        const int s = wave * 4 + s4;
        const int h = s >> 1;
        const int p = s & 1;
        const float4* qp4 = (const float4*)&qn[p * 256 + h * 32];
        #pragma unroll
        for (int j = 0; j < 4; ++j) {
            const int n = lane + 64 * j;
            const float4* kp4 = (const float4*)(keys + ((h * 256 + n) * 2 + p) * 32);
            float dot = 0.0f;
            #pragma unroll
            for (int d4 = 0; d4 < 8; ++d4) {
                const float4 kv = kp4[d4];
                const float4 qf = qp4[d4];
                dot += qf.x * kv.x + qf.y * kv.y + qf.z * kv.z + qf.w * kv.w;
            }
            const unsigned int u  = __float_as_uint(dot);
            const unsigned int kb = (u & 0x80000000u) ? ~u : (u | 0x80000000u);
            cand[s4][j] = ((unsigned long long)kb << 32) | (unsigned int)(255 - n);
        }
    }

    // ---- phase 1 extraction: 4 independent chains interleaved per iteration ----
    float mysc[4]; int myid[4];
    #pragma unroll
    for (int it = 0; it < 16; ++it) {
        #pragma unroll
        for (int s4 = 0; s4 < 4; ++s4) {
            unsigned long long lm = cand[s4][0];
            #pragma unroll
            for (int j = 1; j < 4; ++j) lm = (cand[s4][j] > lm) ? cand[s4][j] : lm;
            unsigned int r = (unsigned int)(lm >> 32);
            #pragma unroll
            for (int off = 32; off > 0; off >>= 1) {
                const unsigned int o = __shfl_xor(r, off);
                r = (o > r) ? o : r;
            }
            const unsigned long long ball = __ballot((unsigned int)(lm >> 32) == r);
            const int wl = __ffsll(ball) - 1;
            const unsigned long long win = __shfl(lm, wl);
            if (lane == wl) {
                #pragma unroll
                for (int j = 0; j < 4; ++j) if (cand[s4][j] == win) cand[s4][j] = 0ULL;
            }
            if (lane == it) {
                const unsigned int kb = (unsigned int)(win >> 32);
                const unsigned int u  = (kb & 0x80000000u) ? (kb & 0x7FFFFFFFu) : ~kb;
                mysc[s4] = __uint_as_float(u);
                myid[s4] = 255 - (int)(win & 0xFFu);
            }
        }
    }
    if (lane < 16) {
        #pragma unroll
        for (int s4 = 0; s4 < 4; ++s4) {
            sTopS[wave * 4 + s4][lane] = mysc[s4];
            sTopI[wave * 4 + s4][lane] = myid[s4];
        }
    }
    __syncthreads();

    // ---- phase 2: 2 combined heads per wave, interleaved extraction + softmax ----
    unsigned long long c2[2][4];
    #pragma unroll
    for (int r2 = 0; r2 < 2; ++r2) {
        const int hh = wave * 2 + r2;
        const int ha = hh >> 1;
        const int p  = hh & 1;
        const int sa = ha * 2 + p;
        const int sb = (ha + 4) * 2 + p;
        const float sAv = sTopS[sa][lane >> 2];
        #pragma unroll
        for (int j = 0; j < 4; ++j) {
            const int c = lane * 4 + j;          // c = i*16 + jj
            const float sc = sAv + sTopS[sb][c & 15];
            const unsigned int u  = __float_as_uint(sc);
            const unsigned int kb = (u & 0x80000000u) ? ~u : (u | 0x80000000u);
            c2[r2][j] = ((unsigned long long)kb << 32) | (unsigned int)(255 - c);
        }
    }
    float mx2[2], ssum2[2] = {0.0f, 0.0f};
    float mysc2[2]; int myc2[2];
    #pragma unroll
    for (int it = 0; it < 16; ++it) {
        #pragma unroll
        for (int r2 = 0; r2 < 2; ++r2) {
            unsigned long long lm = c2[r2][0];
            #pragma unroll
            for (int j = 1; j < 4; ++j) lm = (c2[r2][j] > lm) ? c2[r2][j] : lm;
            unsigned int r = (unsigned int)(lm >> 32);
            #pragma unroll
            for (int off = 32; off > 0; off >>= 1) {
                const unsigned int o = __shfl_xor(r, off);
                r = (o > r) ? o : r;
            }
            const unsigned long long ball = __ballot((unsigned int)(lm >> 32) == r);
            const int wl = __ffsll(ball) - 1;
            const unsigned long long win = __shfl(lm, wl);
            if (lane == wl) {
                #pragma unroll
                for (int j = 0; j < 4; ++j) if (c2[r2][j] == win) c2[r2][j] = 0ULL;
            }
            // winner score decodable from r by ALL lanes (wave-uniform)
            const unsigned int us = (r & 0x80000000u) ? (r & 0x7FFFFFFFu) : ~r;
            const float sc = __uint_as_float(us);
            if (it == 0) mx2[r2] = sc;
            ssum2[r2] += __expf(sc - mx2[r2]);
            if (lane == it) {
                mysc2[r2] = sc;
                myc2[r2]  = 255 - (int)(win & 0xFFu);
            }
        }
    }
    if (lane < 16) {
        #pragma unroll
        for (int r2 = 0; r2 < 2; ++r2) {
            const int hh = wave * 2 + r2;
            const int ha = hh >> 1;
            const int p  = hh & 1;
            const int sa = ha * 2 + p;
            const int sb = (ha + 4) * 2 + p;
            const int c  = myc2[r2];
            wW[hh * 16 + lane] = __expf(mysc2[r2] - mx2[r2]) / ssum2[r2];
            wI[hh * 16 + lane] = sTopI[sa][c >> 4] * 256 + sTopI[sb][c & 15];
        }
    }
    __syncthreads();

    // ---- phase 3: weighted gather of 128 value rows ----
    float2 acc = make_float2(0.0f, 0.0f);
    const float2* vb = (const float2*)values;
    #pragma unroll 8
    for (int k = 0; k < 128; ++k) {
        const float w   = wW[k];
        const int   idx = wI[k];
        const float2 v  = vb[idx * 256 + tid];
        acc.x += w * v.x;
        acc.y += w * v.y;
    }
    *(float2*)(out + tok * 512 + tid * 2) = acc;
}

extern "C" void kernel_launch(void* const* d_in, const int* in_sizes, int n_in,
                              void* d_out, int out_size, void* d_ws, size_t ws_size,
                              hipStream_t stream) {
    const float* x      = (const float*)d_in[0];
    const float* Wq     = (const float*)d_in[1];
    const float* gamma  = (const float*)d_in[2];
    const float* beta   = (const float*)d_in[3];
    const float* keys   = (const float*)d_in[4];
    const float* values = (const float*)d_in[5];
    float* out = (float*)d_out;

    float* q     = (float*)d_ws;               // 4096*512 floats
    float* stats = q + NTOK * 512;             // 1024 floats (sum, sumsq)
    float* mr    = stats + 1024;               // 1024 floats (mean, rstd)

    k_zero<<<1, 1024, 0, stream>>>(stats);
    dim3 g1(NTOK / 64, 512 / 64);
    k_gemm<<<g1, 256, 0, stream>>>(x, Wq, q);
    k_stats<<<NTOK / 64, 256, 0, stream>>>(q, stats);
    k_finalize<<<1, 512, 0, stream>>>(stats, mr);
    k_pkm<<<NTOK, 256, 0, stream>>>(q, mr, gamma, beta, keys, values, out);
}

// Round 11
// 554.706 us; speedup vs baseline: 3.6655x; 3.6655x over previous
//
#include <hip/hip_runtime.h>

#define NTOK 4096
#define EPS 1e-5f

// ---------------- K0: zero the stats accumulators ----------------
__global__ void k_zero(float* __restrict__ stats) {
    int t = blockIdx.x * blockDim.x + threadIdx.x;
    if (t < 1024) stats[t] = 0.0f;
}

// ---------------- K1: q = x @ Wq^T  (M=4096,N=512,K=512, all row-major K-contiguous)
__global__ __launch_bounds__(256) void k_gemm(const float* __restrict__ A,
                                              const float* __restrict__ B,
                                              float* __restrict__ C) {
    __shared__ float As[32][68];   // transposed: As[k][row]
    __shared__ float Bs[32][68];
    const int tid  = threadIdx.x;
    const int row0 = blockIdx.x * 64;
    const int col0 = blockIdx.y * 64;
    const int lr = tid >> 3;          // 0..31
    const int lc = (tid & 7) << 2;    // 0,4,...,28
    const int tx = tid & 15;
    const int ty = tid >> 4;
    float acc[4][4] = {};
    for (int kc = 0; kc < 512; kc += 32) {
        float4 a0 = *(const float4*)(A + (row0 + lr)      * 512 + kc + lc);
        float4 a1 = *(const float4*)(A + (row0 + lr + 32) * 512 + kc + lc);
        float4 b0 = *(const float4*)(B + (col0 + lr)      * 512 + kc + lc);
        float4 b1 = *(const float4*)(B + (col0 + lr + 32) * 512 + kc + lc);
        __syncthreads();
        As[lc + 0][lr] = a0.x; As[lc + 1][lr] = a0.y; As[lc + 2][lr] = a0.z; As[lc + 3][lr] = a0.w;
        As[lc + 0][lr + 32] = a1.x; As[lc + 1][lr + 32] = a1.y; As[lc + 2][lr + 32] = a1.z; As[lc + 3][lr + 32] = a1.w;
        Bs[lc + 0][lr] = b0.x; Bs[lc + 1][lr] = b0.y; Bs[lc + 2][lr] = b0.z; Bs[lc + 3][lr] = b0.w;
        Bs[lc + 0][lr + 32] = b1.x; Bs[lc + 1][lr + 32] = b1.y; Bs[lc + 2][lr + 32] = b1.z; Bs[lc + 3][lr + 32] = b1.w;
        __syncthreads();
        #pragma unroll
        for (int k = 0; k < 32; ++k) {
            const float4 av = *(const float4*)&As[k][ty << 2];
            const float4 bv = *(const float4*)&Bs[k][tx << 2];
            const float a[4] = {av.x, av.y, av.z, av.w};
            const float b[4] = {bv.x, bv.y, bv.z, bv.w};
            #pragma unroll
            for (int i = 0; i < 4; ++i)
                #pragma unroll
                for (int j = 0; j < 4; ++j)
                    acc[i][j] += a[i] * b[j];
        }
    }
    #pragma unroll
    for (int i = 0; i < 4; ++i) {
        float4 v = make_float4(acc[i][0], acc[i][1], acc[i][2], acc[i][3]);
        *(float4*)(C + (row0 + ty * 4 + i) * 512 + col0 + (tx << 2)) = v;
    }
}

// ---------------- K2: per-feature sum / sumsq over 4096 rows (atomics) ----------------
__global__ __launch_bounds__(256) void k_stats(const float* __restrict__ q,
                                               float* __restrict__ stats) {
    const int t  = threadIdx.x;
    const int r0 = blockIdx.x * 64;
    float s0 = 0.f, q0 = 0.f, s1 = 0.f, q1 = 0.f;
    for (int r = 0; r < 64; ++r) {
        const float a = q[(r0 + r) * 512 + t];
        const float b = q[(r0 + r) * 512 + 256 + t];
        s0 += a; q0 += a * a;
        s1 += b; q1 += b * b;
    }
    atomicAdd(&stats[t], s0);
    atomicAdd(&stats[t + 256], s1);
    atomicAdd(&stats[512 + t], q0);
    atomicAdd(&stats[512 + t + 256], q1);
}

// ---------------- K2b: finalize mean / rstd ----------------
__global__ void k_finalize(const float* __restrict__ stats, float* __restrict__ mr) {
    const int f = threadIdx.x;   // 512 threads
    const float mean = stats[f] * (1.0f / 4096.0f);
    const float var  = stats[512 + f] * (1.0f / 4096.0f) - mean * mean;
    mr[f]       = mean;
    mr[512 + f] = rsqrtf(var + EPS);
}

// monotonic map: larger float => larger uint
__device__ __forceinline__ unsigned int fmono(float x) {
    const unsigned int u = __float_as_uint(x);
    return (u & 0x80000000u) ? ~u : (u | 0x80000000u);
}

// ---------------- K3: fused per-token PKM, 4 waves, u32-packed interleaved top-k ----------------
__global__ __launch_bounds__(256, 4) void k_pkm(
    const float* __restrict__ q,
    const float* __restrict__ mr,
    const float* __restrict__ gamma,
    const float* __restrict__ beta,
    const float* __restrict__ keys,
    const float* __restrict__ values,
    float* __restrict__ out)
{
    __shared__ float qn[512];
    __shared__ float sTopS[16][16];
    __shared__ int   sTopI[16][16];
    __shared__ float wW[128];
    __shared__ int   wI[128];

    const int tok  = blockIdx.x;
    const int tid  = threadIdx.x;
    const int lane = tid & 63;
    const int wave = tid >> 6;       // 0..3

    // normalize this token's q row
    {
        const float v0 = q[tok * 512 + tid];
        const float v1 = q[tok * 512 + 256 + tid];
        qn[tid]       = (v0 - mr[tid]) * mr[512 + tid] * gamma[tid] + beta[tid];
        qn[tid + 256] = (v1 - mr[tid + 256]) * mr[512 + tid + 256] * gamma[tid + 256] + beta[tid + 256];
    }
    __syncthreads();

    // ---- phase 1 dots: 4 slices per wave -> packed u32 cand[4][4] ----
    // key = (monotonic_score & 0xFFFFFF00) | (255 - n): select on truncated score,
    // tie-break lower index; index exact, score recomputed exactly afterwards.
    unsigned int cand[4][4];
    #pragma unroll
    for (int s4 = 0; s4 < 4; ++s4) {
        const int s = wave * 4 + s4;
        const int h = s >> 1;
        const int p = s & 1;
        const float4* qp4 = (const float4*)&qn[p * 256 + h * 32];
        #pragma unroll
        for (int j = 0; j < 4; ++j) {
            const int n = lane + 64 * j;
            const float4* kp4 = (const float4*)(keys + ((h * 256 + n) * 2 + p) * 32);
            float dot = 0.0f;
            #pragma unroll
            for (int d4 = 0; d4 < 8; ++d4) {
                const float4 kv = kp4[d4];
                const float4 qf = qp4[d4];
                dot += qf.x * kv.x + qf.y * kv.y + qf.z * kv.z + qf.w * kv.w;
            }
            cand[s4][j] = (fmono(dot) & 0xFFFFFF00u) | (unsigned int)(255 - n);
        }
    }

    // ---- phase 1 extraction: 4 interleaved chains; lane s4*16+it captures winner ----
    unsigned int mywin1 = 0;
    #pragma unroll
    for (int it = 0; it < 16; ++it) {
        #pragma unroll
        for (int s4 = 0; s4 < 4; ++s4) {
            unsigned int lm = cand[s4][0];
            #pragma unroll
            for (int j = 1; j < 4; ++j) lm = (cand[s4][j] > lm) ? cand[s4][j] : lm;
            #pragma unroll
            for (int off = 32; off > 0; off >>= 1) {
                const unsigned int o = __shfl_xor(lm, off);
                lm = (o > lm) ? o : lm;
            }
            if (lane == s4 * 16 + it) mywin1 = lm;
            #pragma unroll
            for (int j = 0; j < 4; ++j) if (cand[s4][j] == lm) cand[s4][j] = 0u;
        }
    }
    // exact score recovery: every lane recomputes ONE winner dot (all 64 parallel)
    {
        const int s = wave * 4 + (lane >> 4);
        const int h = s >> 1;
        const int p = s & 1;
        const int n = 255 - (int)(mywin1 & 0xFFu);
        const float4* qp4 = (const float4*)&qn[p * 256 + h * 32];
        const float4* kp4 = (const float4*)(keys + ((h * 256 + n) * 2 + p) * 32);
        float dot = 0.0f;
        #pragma unroll
        for (int d4 = 0; d4 < 8; ++d4) {
            const float4 kv = kp4[d4];
            const float4 qf = qp4[d4];
            dot += qf.x * kv.x + qf.y * kv.y + qf.z * kv.z + qf.w * kv.w;
        }
        sTopS[s][lane & 15] = dot;
        sTopI[s][lane & 15] = n;
    }
    __syncthreads();

    // ---- phase 2: 2 combined heads per wave, interleaved; lane r2*16+it captures ----
    unsigned int c2[2][4];
    #pragma unroll
    for (int r2 = 0; r2 < 2; ++r2) {
        const int hh = wave * 2 + r2;        // hh = ha*2 + p
        const int ha = hh >> 1;
        const int p  = hh & 1;
        const int sa = ha * 2 + p;
        const int sb = (ha + 4) * 2 + p;
        const float sAv = sTopS[sa][lane >> 2];
        #pragma unroll
        for (int j = 0; j < 4; ++j) {
            const int c = lane * 4 + j;      // c = i*16 + jj
            const float sc = sAv + sTopS[sb][c & 15];
            c2[r2][j] = (fmono(sc) & 0xFFFFFF00u) | (unsigned int)(255 - c);
        }
    }
    unsigned int mywin2 = 0;
    #pragma unroll
    for (int it = 0; it < 16; ++it) {
        #pragma unroll
        for (int r2 = 0; r2 < 2; ++r2) {
            unsigned int lm = c2[r2][0];
            #pragma unroll
            for (int j = 1; j < 4; ++j) lm = (c2[r2][j] > lm) ? c2[r2][j] : lm;
            #pragma unroll
            for (int off = 32; off > 0; off >>= 1) {
                const unsigned int o = __shfl_xor(lm, off);
                lm = (o > lm) ? o : lm;
            }
            if (lane == r2 * 16 + it) mywin2 = lm;
            #pragma unroll
            for (int j = 0; j < 4; ++j) if (c2[r2][j] == lm) c2[r2][j] = 0u;
        }
    }
    // exact softmax: lanes 0..31 each own one winner; group-leader holds the max
    if (lane < 32) {
        const int r2 = lane >> 4;
        const int hh = wave * 2 + r2;
        const int ha = hh >> 1;
        const int p  = hh & 1;
        const int sa = ha * 2 + p;
        const int sb = (ha + 4) * 2 + p;
        const int c  = 255 - (int)(mywin2 & 0xFFu);
        const float sc = sTopS[sa][c >> 4] + sTopS[sb][c & 15];
        const float mx = __shfl(sc, lane & 48);        // group leader (it==0) = max
        const float e  = __expf(sc - mx);
        float ssum = e;
        #pragma unroll
        for (int off = 1; off < 16; off <<= 1) ssum += __shfl_xor(ssum, off);
        wW[hh * 16 + (lane & 15)] = e / ssum;
        wI[hh * 16 + (lane & 15)] = sTopI[sa][c >> 4] * 256 + sTopI[sb][c & 15];
    }
    __syncthreads();

    // ---- phase 3: weighted gather of 128 value rows ----
    float2 acc = make_float2(0.0f, 0.0f);
    const float2* vb = (const float2*)values;
    #pragma unroll 8
    for (int k = 0; k < 128; ++k) {
        const float w   = wW[k];
        const int   idx = wI[k];
        const float2 v  = vb[idx * 256 + tid];
        acc.x += w * v.x;
        acc.y += w * v.y;
    }
    *(float2*)(out + tok * 512 + tid * 2) = acc;
}

extern "C" void kernel_launch(void* const* d_in, const int* in_sizes, int n_in,
                              void* d_out, int out_size, void* d_ws, size_t ws_size,
                              hipStream_t stream) {
    const float* x      = (const float*)d_in[0];
    const float* Wq     = (const float*)d_in[1];
    const float* gamma  = (const float*)d_in[2];
    const float* beta   = (const float*)d_in[3];
    const float* keys   = (const float*)d_in[4];
    const float* values = (const float*)d_in[5];
    float* out = (float*)d_out;

    float* q     = (float*)d_ws;               // 4096*512 floats
    float* stats = q + NTOK * 512;             // 1024 floats (sum, sumsq)
    float* mr    = stats + 1024;               // 1024 floats (mean, rstd)

    k_zero<<<1, 1024, 0, stream>>>(stats);
    dim3 g1(NTOK / 64, 512 / 64);
    k_gemm<<<g1, 256, 0, stream>>>(x, Wq, q);
    k_stats<<<NTOK / 64, 256, 0, stream>>>(q, stats);
    k_finalize<<<1, 512, 0, stream>>>(stats, mr);
    k_pkm<<<NTOK, 256, 0, stream>>>(q, mr, gamma, beta, keys, values, out);
}

// Round 12
// 538.558 us; speedup vs baseline: 3.7755x; 1.0300x over previous
//
#include <hip/hip_runtime.h>

#define NTOK 4096
#define EPS 1e-5f

// ---------------- K0: zero the stats accumulators ----------------
__global__ void k_zero(float* __restrict__ stats) {
    int t = blockIdx.x * blockDim.x + threadIdx.x;
    if (t < 1024) stats[t] = 0.0f;
}

// ---------------- K1: q = x @ Wq^T + fused column stats ----------------
// M=4096, N=512, K=512, all row-major K-contiguous.
__global__ __launch_bounds__(256) void k_gemm(const float* __restrict__ A,
                                              const float* __restrict__ B,
                                              float* __restrict__ C,
                                              float* __restrict__ stats) {
    __shared__ float As[32][68];   // transposed: As[k][row]
    __shared__ float Bs[32][68];
    const int tid  = threadIdx.x;
    const int row0 = blockIdx.x * 64;
    const int col0 = blockIdx.y * 64;
    const int lr = tid >> 3;          // 0..31
    const int lc = (tid & 7) << 2;    // 0,4,...,28
    const int tx = tid & 15;
    const int ty = tid >> 4;
    float acc[4][4] = {};
    for (int kc = 0; kc < 512; kc += 32) {
        float4 a0 = *(const float4*)(A + (row0 + lr)      * 512 + kc + lc);
        float4 a1 = *(const float4*)(A + (row0 + lr + 32) * 512 + kc + lc);
        float4 b0 = *(const float4*)(B + (col0 + lr)      * 512 + kc + lc);
        float4 b1 = *(const float4*)(B + (col0 + lr + 32) * 512 + kc + lc);
        __syncthreads();
        As[lc + 0][lr] = a0.x; As[lc + 1][lr] = a0.y; As[lc + 2][lr] = a0.z; As[lc + 3][lr] = a0.w;
        As[lc + 0][lr + 32] = a1.x; As[lc + 1][lr + 32] = a1.y; As[lc + 2][lr + 32] = a1.z; As[lc + 3][lr + 32] = a1.w;
        Bs[lc + 0][lr] = b0.x; Bs[lc + 1][lr] = b0.y; Bs[lc + 2][lr] = b0.z; Bs[lc + 3][lr] = b0.w;
        Bs[lc + 0][lr + 32] = b1.x; Bs[lc + 1][lr + 32] = b1.y; Bs[lc + 2][lr + 32] = b1.z; Bs[lc + 3][lr + 32] = b1.w;
        __syncthreads();
        #pragma unroll
        for (int k = 0; k < 32; ++k) {
            const float4 av = *(const float4*)&As[k][ty << 2];
            const float4 bv = *(const float4*)&Bs[k][tx << 2];
            const float a[4] = {av.x, av.y, av.z, av.w};
            const float b[4] = {bv.x, bv.y, bv.z, bv.w};
            #pragma unroll
            for (int i = 0; i < 4; ++i)
                #pragma unroll
                for (int j = 0; j < 4; ++j)
                    acc[i][j] += a[i] * b[j];
        }
    }
    #pragma unroll
    for (int i = 0; i < 4; ++i) {
        float4 v = make_float4(acc[i][0], acc[i][1], acc[i][2], acc[i][3]);
        *(float4*)(C + (row0 + ty * 4 + i) * 512 + col0 + (tx << 2)) = v;
    }
    // ---- fused per-column partial stats for this block's 64 rows ----
    __syncthreads();                       // done with As/Bs; reuse as reduce buffers
    float* redS = &As[0][0];               // [16][64] floats
    float* redQ = &Bs[0][0];               // [16][64] floats
    #pragma unroll
    for (int j = 0; j < 4; ++j) {
        const float s = acc[0][j] + acc[1][j] + acc[2][j] + acc[3][j];
        const float qq = acc[0][j] * acc[0][j] + acc[1][j] * acc[1][j]
                       + acc[2][j] * acc[2][j] + acc[3][j] * acc[3][j];
        redS[ty * 64 + tx * 4 + j] = s;
        redQ[ty * 64 + tx * 4 + j] = qq;
    }
    __syncthreads();
    if (tid < 64) {
        float a = 0.0f, b = 0.0f;
        #pragma unroll
        for (int t = 0; t < 16; ++t) {
            a += redS[t * 64 + tid];
            b += redQ[t * 64 + tid];
        }
        atomicAdd(&stats[col0 + tid], a);
        atomicAdd(&stats[512 + col0 + tid], b);
    }
}

// ---------------- K2b: finalize mean / rstd ----------------
__global__ void k_finalize(const float* __restrict__ stats, float* __restrict__ mr) {
    const int f = threadIdx.x;   // 512 threads
    const float mean = stats[f] * (1.0f / 4096.0f);
    const float var  = stats[512 + f] * (1.0f / 4096.0f) - mean * mean;
    mr[f]       = mean;
    mr[512 + f] = rsqrtf(var + EPS);
}

// monotonic map: larger float => larger uint
__device__ __forceinline__ unsigned int fmono(float x) {
    const unsigned int u = __float_as_uint(x);
    return (u & 0x80000000u) ? ~u : (u | 0x80000000u);
}

// wave-wide max of a u32 via DPP (VALU pipe, no DS), result uniform via readlane.
// row_ror 1/2/4/8 reduce within 16-lane rows; row_bcast15/31 fold rows; lane 63
// holds the global max. bound_ctrl=true feeds 0 to lanes with no source (max-safe).
__device__ __forceinline__ unsigned int wave_max_u32(unsigned int m) {
    unsigned int t;
    t = (unsigned int)__builtin_amdgcn_update_dpp(0, (int)m, 0x121, 0xF, 0xF, true); m = t > m ? t : m;
    t = (unsigned int)__builtin_amdgcn_update_dpp(0, (int)m, 0x122, 0xF, 0xF, true); m = t > m ? t : m;
    t = (unsigned int)__builtin_amdgcn_update_dpp(0, (int)m, 0x124, 0xF, 0xF, true); m = t > m ? t : m;
    t = (unsigned int)__builtin_amdgcn_update_dpp(0, (int)m, 0x128, 0xF, 0xF, true); m = t > m ? t : m;
    t = (unsigned int)__builtin_amdgcn_update_dpp(0, (int)m, 0x142, 0xF, 0xF, true); m = t > m ? t : m;  // bcast15
    t = (unsigned int)__builtin_amdgcn_update_dpp(0, (int)m, 0x143, 0xF, 0xF, true); m = t > m ? t : m;  // bcast31
    return (unsigned int)__builtin_amdgcn_readlane((int)m, 63);
}

// ---------------- K3: fused per-token PKM, 4 waves, DPP-reduced top-k ----------------
__global__ __launch_bounds__(256, 4) void k_pkm(
    const float* __restrict__ q,
    const float* __restrict__ mr,
    const float* __restrict__ gamma,
    const float* __restrict__ beta,
    const float* __restrict__ keys,
    const float* __restrict__ values,
    float* __restrict__ out)
{
    __shared__ float qn[512];
    __shared__ float sTopS[16][16];
    __shared__ int   sTopI[16][16];
    __shared__ float wW[128];
    __shared__ int   wI[128];

    const int tok  = blockIdx.x;
    const int tid  = threadIdx.x;
    const int lane = tid & 63;
    const int wave = tid >> 6;       // 0..3

    // normalize this token's q row
    {
        const float v0 = q[tok * 512 + tid];
        const float v1 = q[tok * 512 + 256 + tid];
        qn[tid]       = (v0 - mr[tid]) * mr[512 + tid] * gamma[tid] + beta[tid];
        qn[tid + 256] = (v1 - mr[tid + 256]) * mr[512 + tid + 256] * gamma[tid + 256] + beta[tid + 256];
    }
    __syncthreads();

    // ---- phase 1 dots: 4 slices per wave -> packed u32 cand[4][4] ----
    // key = (monotonic_score & 0xFFFFFF00) | (255 - n): select on truncated score,
    // tie-break lower index; index exact, score recomputed exactly afterwards.
    unsigned int cand[4][4];
    #pragma unroll
    for (int s4 = 0; s4 < 4; ++s4) {
        const int s = wave * 4 + s4;
        const int h = s >> 1;
        const int p = s & 1;
        const float4* qp4 = (const float4*)&qn[p * 256 + h * 32];
        #pragma unroll
        for (int j = 0; j < 4; ++j) {
            const int n = lane + 64 * j;
            const float4* kp4 = (const float4*)(keys + ((h * 256 + n) * 2 + p) * 32);
            float dot = 0.0f;
            #pragma unroll
            for (int d4 = 0; d4 < 8; ++d4) {
                const float4 kv = kp4[d4];
                const float4 qf = qp4[d4];
                dot += qf.x * kv.x + qf.y * kv.y + qf.z * kv.z + qf.w * kv.w;
            }
            cand[s4][j] = (fmono(dot) & 0xFFFFFF00u) | (unsigned int)(255 - n);
        }
    }

    // ---- phase 1 extraction: 4 interleaved DPP chains; lane s4*16+it captures ----
    unsigned int mywin1 = 0;
    #pragma unroll
    for (int it = 0; it < 16; ++it) {
        #pragma unroll
        for (int s4 = 0; s4 < 4; ++s4) {
            unsigned int lm = cand[s4][0];
            #pragma unroll
            for (int j = 1; j < 4; ++j) lm = (cand[s4][j] > lm) ? cand[s4][j] : lm;
            const unsigned int win = wave_max_u32(lm);
            if (lane == s4 * 16 + it) mywin1 = win;
            #pragma unroll
            for (int j = 0; j < 4; ++j) if (cand[s4][j] == win) cand[s4][j] = 0u;
        }
    }
    // exact score recovery: every lane recomputes ONE winner dot (all 64 parallel)
    {
        const int s = wave * 4 + (lane >> 4);
        const int h = s >> 1;
        const int p = s & 1;
        const int n = 255 - (int)(mywin1 & 0xFFu);
        const float4* qp4 = (const float4*)&qn[p * 256 + h * 32];
        const float4* kp4 = (const float4*)(keys + ((h * 256 + n) * 2 + p) * 32);
        float dot = 0.0f;
        #pragma unroll
        for (int d4 = 0; d4 < 8; ++d4) {
            const float4 kv = kp4[d4];
            const float4 qf = qp4[d4];
            dot += qf.x * kv.x + qf.y * kv.y + qf.z * kv.z + qf.w * kv.w;
        }
        sTopS[s][lane & 15] = dot;
        sTopI[s][lane & 15] = n;
    }
    __syncthreads();

    // ---- phase 2: 2 combined heads per wave, DPP chains; lane r2*16+it captures ----
    unsigned int c2[2][4];
    #pragma unroll
    for (int r2 = 0; r2 < 2; ++r2) {
        const int hh = wave * 2 + r2;        // hh = ha*2 + p
        const int ha = hh >> 1;
        const int p  = hh & 1;
        const int sa = ha * 2 + p;
        const int sb = (ha + 4) * 2 + p;
        const float sAv = sTopS[sa][lane >> 2];
        #pragma unroll
        for (int j = 0; j < 4; ++j) {
            const int c = lane * 4 + j;      // c = i*16 + jj
            const float sc = sAv + sTopS[sb][c & 15];
            c2[r2][j] = (fmono(sc) & 0xFFFFFF00u) | (unsigned int)(255 - c);
        }
    }
    unsigned int mywin2 = 0;
    #pragma unroll
    for (int it = 0; it < 16; ++it) {
        #pragma unroll
        for (int r2 = 0; r2 < 2; ++r2) {
            unsigned int lm = c2[r2][0];
            #pragma unroll
            for (int j = 1; j < 4; ++j) lm = (c2[r2][j] > lm) ? c2[r2][j] : lm;
            const unsigned int win = wave_max_u32(lm);
            if (lane == r2 * 16 + it) mywin2 = win;
            #pragma unroll
            for (int j = 0; j < 4; ++j) if (c2[r2][j] == win) c2[r2][j] = 0u;
        }
    }
    // exact softmax: lanes 0..31 each own one winner; group-leader (it==0) holds max
    if (lane < 32) {
        const int r2 = lane >> 4;
        const int hh = wave * 2 + r2;
        const int ha = hh >> 1;
        const int p  = hh & 1;
        const int sa = ha * 2 + p;
        const int sb = (ha + 4) * 2 + p;
        const int c  = 255 - (int)(mywin2 & 0xFFu);
        const float sc = sTopS[sa][c >> 4] + sTopS[sb][c & 15];
        const float mx = __shfl(sc, lane & 48);        // group leader (it==0) = max
        const float e  = __expf(sc - mx);
        float ssum = e;
        #pragma unroll
        for (int off = 1; off < 16; off <<= 1) ssum += __shfl_xor(ssum, off);
        wW[hh * 16 + (lane & 15)] = e / ssum;
        wI[hh * 16 + (lane & 15)] = sTopI[sa][c >> 4] * 256 + sTopI[sb][c & 15];
    }
    __syncthreads();

    // ---- phase 3: weighted gather of 128 value rows ----
    float2 acc = make_float2(0.0f, 0.0f);
    const float2* vb = (const float2*)values;
    #pragma unroll 8
    for (int k = 0; k < 128; ++k) {
        const float w   = wW[k];
        const int   idx = wI[k];
        const float2 v  = vb[idx * 256 + tid];
        acc.x += w * v.x;
        acc.y += w * v.y;
    }
    *(float2*)(out + tok * 512 + tid * 2) = acc;
}

extern "C" void kernel_launch(void* const* d_in, const int* in_sizes, int n_in,
                              void* d_out, int out_size, void* d_ws, size_t ws_size,
                              hipStream_t stream) {
    const float* x      = (const float*)d_in[0];
    const float* Wq     = (const float*)d_in[1];
    const float* gamma  = (const float*)d_in[2];
    const float* beta   = (const float*)d_in[3];
    const float* keys   = (const float*)d_in[4];
    const float* values = (const float*)d_in[5];
    float* out = (float*)d_out;

    float* q     = (float*)d_ws;               // 4096*512 floats
    float* stats = q + NTOK * 512;             // 1024 floats (sum, sumsq)
    float* mr    = stats + 1024;               // 1024 floats (mean, rstd)

    k_zero<<<1, 1024, 0, stream>>>(stats);
    dim3 g1(NTOK / 64, 512 / 64);
    k_gemm<<<g1, 256, 0, stream>>>(x, Wq, q, stats);
    k_finalize<<<1, 512, 0, stream>>>(stats, mr);
    k_pkm<<<NTOK, 256, 0, stream>>>(q, mr, gamma, beta, keys, values, out);
}